// Round 5
// baseline (468.210 us; speedup 1.0000x reference)
//
#include <hip/hip_runtime.h>

// Problem constants
#define N_NODES   300000
#define K_STENCIL 27
#define CIN       32
#define COUT      64
#define BN_EPS    1e-5f

// Workspace layout (bytes):
//   [0, 32768)           : split stats, 64 splits x (sum[64], sumsq[64]) fp32
//   [32768, 33280)       : ab coeffs a[64], b[64] fp32
//   [33280, 143872)      : weightT bf16 [27][64][32]
//   [147456, +19.2MB)    : data bf16 [N][32]  (only if ws_size permits)
#define WS_STATS_OFF 0
#define WS_AB_OFF    32768
#define WS_WT_OFF    33280
#define WS_DATAB_OFF 147456
#define WS_NEEDED    (WS_DATAB_OFF + (size_t)N_NODES * CIN * 2)
#define N_SPLITS     64

typedef short bf16x8 __attribute__((ext_vector_type(8)));
typedef short bf16x4 __attribute__((ext_vector_type(4)));
typedef float f32x4  __attribute__((ext_vector_type(4)));

__device__ __forceinline__ short f2bf_rne(float f) {
    unsigned u = __builtin_bit_cast(unsigned, f);
    u += 0x7fffu + ((u >> 16) & 1u);   // round-to-nearest-even
    return (short)(u >> 16);
}

// ---------------------------------------------------------------------------
__global__ void zero_stats(float* __restrict__ stats) {
    stats[blockIdx.x * blockDim.x + threadIdx.x] = 0.f;   // 32x256 = 8192
}

// ---------------------------------------------------------------------------
// weight [27][32][64] fp32 -> weightT [27][64][32] bf16 (RNE)
// ---------------------------------------------------------------------------
__global__ void prep_weight(const float* __restrict__ w, unsigned short* __restrict__ wT) {
    int t = blockIdx.x * blockDim.x + threadIdx.x;   // 55296
    if (t >= K_STENCIL * COUT * CIN) return;
    int c = t & (CIN - 1);
    int o = (t >> 5) & (COUT - 1);
    int k = t >> 11;
    wT[t] = (unsigned short)f2bf_rne(w[(k * CIN + c) * COUT + o]);
}

// ---------------------------------------------------------------------------
// data fp32 [N][32] -> bf16 [N][32]; 2.4M threads x 4 elems, exact grid
// ---------------------------------------------------------------------------
__global__ __launch_bounds__(256) void prep_data(const float* __restrict__ d,
                                                 unsigned short* __restrict__ o) {
    int i = blockIdx.x * blockDim.x + threadIdx.x;   // f32x4 index
    f32x4 v = ((const f32x4*)d)[i];
    bf16x4 r;
    #pragma unroll
    for (int j = 0; j < 4; ++j) r[j] = f2bf_rne(v[j]);
    ((bf16x4*)o)[i] = r;
}

// ---------------------------------------------------------------------------
// Gather-GEMM (bf16 data) + fused BN stats.
// Block = 256 = 4 waves; wave: 16 nodes x 64 couts. C/D layout self-discovered
// via probe MFMA (D = I*T, T[k][n]=k*16+n). Gather = one 16B bf16x8 per lane.
// ---------------------------------------------------------------------------
__global__ __launch_bounds__(256) void conv_mfma_b(
        const unsigned short* __restrict__ dataB, const int* __restrict__ neigh,
        const unsigned short* __restrict__ wT, float* __restrict__ out,
        float* __restrict__ stats) {
    __shared__ float lsum[COUT];
    __shared__ float lsq[COUT];
    if (threadIdx.x < COUT) { lsum[threadIdx.x] = 0.f; lsq[threadIdx.x] = 0.f; }
    __syncthreads();

    const int wave  = threadIdx.x >> 6;
    const int lane  = threadIdx.x & 63;
    const int row16 = lane & 15;
    const int quad  = lane >> 4;

    // ---- layout probe ----
    bf16x8 ia, tb;
    #pragma unroll
    for (int j = 0; j < 8; ++j) {
        int k = quad * 8 + j;
        ia[j] = (k == row16) ? (short)0x3F80 : (short)0;   // I[m][k]
        tb[j] = f2bf_rne((float)(k * 16 + row16));         // T[k][n], n=row16
    }
    f32x4 pacc = {0.f, 0.f, 0.f, 0.f};
    pacc = __builtin_amdgcn_mfma_f32_16x16x32_bf16(ia, tb, pacc, 0, 0, 0);
    int mrow[4], ncol[4];
    #pragma unroll
    for (int r = 0; r < 4; ++r) {
        int iv = (int)(pacc[r] + 0.5f);
        mrow[r] = (iv >> 4) & 15;
        ncol[r] = iv & 15;
    }

    // ---- main gather-GEMM ----
    const int node   = blockIdx.x * 64 + wave * 16 + row16;
    const bool valid = (node < N_NODES);
    const int nclamp = valid ? node : 0;

    f32x4 acc[4] = {f32x4{0,0,0,0}, f32x4{0,0,0,0}, f32x4{0,0,0,0}, f32x4{0,0,0,0}};
    const int* nrow = neigh + nclamp * K_STENCIL;

    #pragma unroll 9
    for (int k = 0; k < K_STENCIL; ++k) {
        int idx = nrow[k];
        bf16x8 afrag = bf16x8{0,0,0,0,0,0,0,0};
        if (valid && idx >= 0)
            afrag = *(const bf16x8*)(dataB + (size_t)idx * CIN + quad * 8);
        const unsigned short* wk = wT + k * (COUT * CIN) + row16 * CIN + quad * 8;
        #pragma unroll
        for (int ct = 0; ct < 4; ++ct) {
            bf16x8 bfrag = *(const bf16x8*)(wk + ct * 16 * CIN);
            acc[ct] = __builtin_amdgcn_mfma_f32_16x16x32_bf16(afrag, bfrag, acc[ct], 0, 0, 0);
        }
    }

    // ---- epilogue: write + fused stats with discovered (m,n) mapping ----
    const int tilebase = blockIdx.x * 64 + wave * 16;
    #pragma unroll
    for (int ct = 0; ct < 4; ++ct) {
        #pragma unroll
        for (int r = 0; r < 4; ++r) {
            int n_out = tilebase + mrow[r];
            float v = acc[ct][r];
            if (n_out < N_NODES) {
                out[(size_t)n_out * COUT + ct * 16 + ncol[r]] = v;
                atomicAdd(&lsum[ct * 16 + ncol[r]], v);
                atomicAdd(&lsq [ct * 16 + ncol[r]], v * v);
            }
        }
    }

    __syncthreads();
    if (threadIdx.x < 128) {
        int split = blockIdx.x & (N_SPLITS - 1);
        float v = (threadIdx.x < 64) ? lsum[threadIdx.x] : lsq[threadIdx.x - 64];
        atomicAdd(&stats[split * 128 + threadIdx.x], v);
    }
}

// ---------------------------------------------------------------------------
// Fallback (proven R4 path): fp32 gathers, no fused stats
// ---------------------------------------------------------------------------
__global__ __launch_bounds__(256) void conv_mfma_f(
        const float* __restrict__ data, const int* __restrict__ neigh,
        const unsigned short* __restrict__ wT, float* __restrict__ out) {
    const int wave  = threadIdx.x >> 6;
    const int lane  = threadIdx.x & 63;
    const int row16 = lane & 15;
    const int quad  = lane >> 4;

    bf16x8 ia, tb;
    #pragma unroll
    for (int j = 0; j < 8; ++j) {
        int k = quad * 8 + j;
        ia[j] = (k == row16) ? (short)0x3F80 : (short)0;
        tb[j] = f2bf_rne((float)(k * 16 + row16));
    }
    f32x4 pacc = {0.f, 0.f, 0.f, 0.f};
    pacc = __builtin_amdgcn_mfma_f32_16x16x32_bf16(ia, tb, pacc, 0, 0, 0);
    int mrow[4], ncol[4];
    #pragma unroll
    for (int r = 0; r < 4; ++r) {
        int iv = (int)(pacc[r] + 0.5f);
        mrow[r] = (iv >> 4) & 15;
        ncol[r] = iv & 15;
    }

    const int node   = blockIdx.x * 64 + wave * 16 + row16;
    const bool valid = (node < N_NODES);
    const int nclamp = valid ? node : 0;

    f32x4 acc[4] = {f32x4{0,0,0,0}, f32x4{0,0,0,0}, f32x4{0,0,0,0}, f32x4{0,0,0,0}};
    const int* nrow = neigh + nclamp * K_STENCIL;

    #pragma unroll 3
    for (int k = 0; k < K_STENCIL; ++k) {
        int idx = nrow[k];
        bf16x8 afrag;
        if (valid && idx >= 0) {
            const f32x4* drow = (const f32x4*)(data + (size_t)idx * CIN + quad * 8);
            f32x4 lo = drow[0];
            f32x4 hi = drow[1];
            #pragma unroll
            for (int j = 0; j < 4; ++j) {
                afrag[j]     = f2bf_rne(lo[j]);
                afrag[j + 4] = f2bf_rne(hi[j]);
            }
        } else {
            afrag = bf16x8{0,0,0,0,0,0,0,0};
        }
        const unsigned short* wk = wT + k * (COUT * CIN) + row16 * CIN + quad * 8;
        #pragma unroll
        for (int ct = 0; ct < 4; ++ct) {
            bf16x8 bfrag = *(const bf16x8*)(wk + ct * 16 * CIN);
            acc[ct] = __builtin_amdgcn_mfma_f32_16x16x32_bf16(afrag, bfrag, acc[ct], 0, 0, 0);
        }
    }

    const int tilebase = blockIdx.x * 64 + wave * 16;
    #pragma unroll
    for (int ct = 0; ct < 4; ++ct) {
        #pragma unroll
        for (int r = 0; r < 4; ++r) {
            int n_out = tilebase + mrow[r];
            if (n_out < N_NODES)
                out[(size_t)n_out * COUT + ct * 16 + ncol[r]] = acc[ct][r];
        }
    }
}

// ---------------------------------------------------------------------------
// BN stats sweep (fallback path only)
// ---------------------------------------------------------------------------
__global__ __launch_bounds__(256) void stats_pass(const float* __restrict__ out,
                                                  float* __restrict__ stats) {
    __shared__ float lsum[COUT];
    __shared__ float lsq[COUT];
    if (threadIdx.x < COUT) { lsum[threadIdx.x] = 0.f; lsq[threadIdx.x] = 0.f; }
    __syncthreads();

    const int j = threadIdx.x & 15;
    int row = blockIdx.x * 16 + (threadIdx.x >> 4);
    const int rstride = gridDim.x * 16;
    float s0=0,s1=0,s2=0,s3=0,q0=0,q1=0,q2=0,q3=0;
    for (; row < N_NODES; row += rstride) {
        f32x4 v = ((const f32x4*)out)[row * 16 + j];
        s0 += v[0]; q0 += v[0]*v[0];
        s1 += v[1]; q1 += v[1]*v[1];
        s2 += v[2]; q2 += v[2]*v[2];
        s3 += v[3]; q3 += v[3]*v[3];
    }
    atomicAdd(&lsum[j*4+0], s0); atomicAdd(&lsq[j*4+0], q0);
    atomicAdd(&lsum[j*4+1], s1); atomicAdd(&lsq[j*4+1], q1);
    atomicAdd(&lsum[j*4+2], s2); atomicAdd(&lsq[j*4+2], q2);
    atomicAdd(&lsum[j*4+3], s3); atomicAdd(&lsq[j*4+3], q3);
    __syncthreads();

    if (threadIdx.x < 128) {
        int split = blockIdx.x & (N_SPLITS - 1);
        float v = (threadIdx.x < 64) ? lsum[threadIdx.x] : lsq[threadIdx.x - 64];
        atomicAdd(&stats[split * 128 + threadIdx.x], v);
    }
}

// ---------------------------------------------------------------------------
__global__ void finalize_stats(const float* __restrict__ stats,
                               const float* __restrict__ gamma,
                               const float* __restrict__ beta,
                               float* __restrict__ ab) {
    int o = threadIdx.x;  // 64 threads
    if (o >= COUT) return;
    float s = 0.f, q = 0.f;
    for (int sp = 0; sp < N_SPLITS; ++sp) {
        s += stats[sp * 128 + o];
        q += stats[sp * 128 + 64 + o];
    }
    float inv_n = 1.0f / (float)N_NODES;
    float mean = s * inv_n;
    float var  = q * inv_n - mean * mean;
    float a = gamma[o] * rsqrtf(var + BN_EPS);
    float b = beta[o] - mean * a;
    ab[o] = a;
    ab[64 + o] = b;
}

// ---------------------------------------------------------------------------
__global__ __launch_bounds__(256) void bn_relu(float* __restrict__ out,
                                               const float* __restrict__ ab) {
    int i = blockIdx.x * blockDim.x + threadIdx.x;  // float4 index, exact grid
    f32x4 a = ((const f32x4*)ab)[i & 15];
    f32x4 b = ((const f32x4*)(ab + 64))[i & 15];
    f32x4 v = ((f32x4*)out)[i];
    #pragma unroll
    for (int j = 0; j < 4; ++j) {
        float y = v[j] * a[j] + b[j];
        v[j] = y > 0.f ? y : 0.f;
    }
    ((f32x4*)out)[i] = v;
}

// ---------------------------------------------------------------------------
extern "C" void kernel_launch(void* const* d_in, const int* in_sizes, int n_in,
                              void* d_out, int out_size, void* d_ws, size_t ws_size,
                              hipStream_t stream) {
    const float* data   = (const float*)d_in[0];
    const int*   neigh  = (const int*)d_in[1];     // int32 on device
    const float* weight = (const float*)d_in[2];
    const float* gamma  = (const float*)d_in[3];
    const float* beta   = (const float*)d_in[4];
    float* out = (float*)d_out;

    char* ws = (char*)d_ws;
    float*          stats = (float*)(ws + WS_STATS_OFF);
    float*          ab    = (float*)(ws + WS_AB_OFF);
    unsigned short* wT    = (unsigned short*)(ws + WS_WT_OFF);
    unsigned short* dataB = (unsigned short*)(ws + WS_DATAB_OFF);

    zero_stats<<<32, 256, 0, stream>>>(stats);
    prep_weight<<<(K_STENCIL * COUT * CIN + 255) / 256, 256, 0, stream>>>(weight, wT);

    const int grid = (N_NODES + 63) / 64;  // 4688
    if (ws_size >= WS_NEEDED) {
        // bf16-data path: halve gather bytes, fuse stats into conv epilogue
        prep_data<<<N_NODES * CIN / 4 / 256, 256, 0, stream>>>(data, dataB);  // 9375
        conv_mfma_b<<<grid, 256, 0, stream>>>(dataB, neigh, wT, out, stats);
    } else {
        conv_mfma_f<<<grid, 256, 0, stream>>>(data, neigh, wT, out);
        stats_pass<<<1024, 256, 0, stream>>>(out, stats);
    }

    finalize_stats<<<1, 64, 0, stream>>>(stats, gamma, beta, ab);

    int total4 = N_NODES * COUT / 4;  // 4,800,000
    bn_relu<<<total4 / 256, 256, 0, stream>>>(out, ab);
}

// Round 6
// 398.252 us; speedup vs baseline: 1.1757x; 1.1757x over previous
//
#include <hip/hip_runtime.h>

// Problem constants
#define N_NODES   300000
#define K_STENCIL 27
#define CIN       32
#define COUT      64
#define BN_EPS    1e-5f

// Workspace layout (bytes):
//   [0, 32768)           : split stats, 64 splits x (sum[64], sumsq[64]) fp32
//   [32768, 33280)       : ab coeffs a[64], b[64] fp32
//   [33280, 143872)      : weightT bf16 [27][64][32]
#define WS_STATS_OFF 0
#define WS_AB_OFF    32768
#define WS_WT_OFF    33280
#define N_SPLITS     64

typedef short bf16x8 __attribute__((ext_vector_type(8)));
typedef float f32x4  __attribute__((ext_vector_type(4)));

__device__ __forceinline__ short f2bf_rne(float f) {
    unsigned u = __builtin_bit_cast(unsigned, f);
    u += 0x7fffu + ((u >> 16) & 1u);   // round-to-nearest-even
    return (short)(u >> 16);
}

// ---------------------------------------------------------------------------
// prep: zero split-stats (8192 floats) + weight [27][32][64] fp32 ->
// weightT [27][64][32] bf16. 55296 weight elems; 217 blocks x 256.
// ---------------------------------------------------------------------------
__global__ void prep(const float* __restrict__ w, unsigned short* __restrict__ wT,
                     float* __restrict__ stats) {
    int t = blockIdx.x * blockDim.x + threadIdx.x;
    if (t < N_SPLITS * 128) stats[t] = 0.f;
    if (t < K_STENCIL * COUT * CIN) {
        int c = t & (CIN - 1);
        int o = (t >> 5) & (COUT - 1);
        int k = t >> 11;
        wT[t] = (unsigned short)f2bf_rne(w[(k * CIN + c) * COUT + o]);
    }
}

// ---------------------------------------------------------------------------
// Gather-GEMM via MFMA, software-pipelined in 3 groups of 9 stencil taps:
// per group, issue all 9 neigh-index loads, then all 18 gather dwordx4 loads
// (into live register arrays), then drain through 36 MFMAs. launch_bounds
// (256,2) gives the allocator a 256-VGPR budget so loads stay in flight —
// R5 showed the compiler register-minimizes to ~2 outstanding gathers
// otherwise (VGPR=32), which caps BW at ~2.3 TB/s (latency-bound).
// C/D layout self-discovered via probe MFMA (R4-proven).
// ---------------------------------------------------------------------------
__global__ __launch_bounds__(256, 2) void conv_mfma(
        const float* __restrict__ data, const int* __restrict__ neigh,
        const unsigned short* __restrict__ wT, float* __restrict__ out) {
    const int wave  = threadIdx.x >> 6;
    const int lane  = threadIdx.x & 63;
    const int row16 = lane & 15;
    const int quad  = lane >> 4;

    // ---- layout probe: D = I*T, T[k][n]=k*16+n -> slot value encodes (m,n)
    bf16x8 ia, tb;
    #pragma unroll
    for (int j = 0; j < 8; ++j) {
        int k = quad * 8 + j;
        ia[j] = (k == row16) ? (short)0x3F80 : (short)0;
        tb[j] = f2bf_rne((float)(k * 16 + row16));
    }
    f32x4 pacc = {0.f, 0.f, 0.f, 0.f};
    pacc = __builtin_amdgcn_mfma_f32_16x16x32_bf16(ia, tb, pacc, 0, 0, 0);
    int mrow[4], ncol[4];
    #pragma unroll
    for (int r = 0; r < 4; ++r) {
        int iv = (int)(pacc[r] + 0.5f);
        mrow[r] = (iv >> 4) & 15;
        ncol[r] = iv & 15;
    }

    // ---- main gather-GEMM ----
    const int node   = blockIdx.x * 64 + wave * 16 + row16;
    const bool valid = (node < N_NODES);
    const int nclamp = valid ? node : 0;

    f32x4 acc[4] = {f32x4{0,0,0,0}, f32x4{0,0,0,0}, f32x4{0,0,0,0}, f32x4{0,0,0,0}};
    const int* nrow = neigh + nclamp * K_STENCIL;

    #pragma unroll
    for (int g = 0; g < 3; ++g) {
        // 1) neighbor indices for this group
        int kid[9];
        #pragma unroll
        for (int j = 0; j < 9; ++j) kid[j] = nrow[g * 9 + j];

        // 2) issue all gathers (2x f32x4 per tap) into live arrays
        f32x4 lo[9], hi[9];
        #pragma unroll
        for (int j = 0; j < 9; ++j) {
            int idx = kid[j];
            if (valid && idx >= 0) {
                const f32x4* drow = (const f32x4*)(data + (size_t)idx * CIN + quad * 8);
                lo[j] = drow[0];
                hi[j] = drow[1];
            } else {
                lo[j] = f32x4{0, 0, 0, 0};
                hi[j] = f32x4{0, 0, 0, 0};
            }
        }

        // 3) drain: pack bf16 + 4 MFMAs per tap
        #pragma unroll
        for (int j = 0; j < 9; ++j) {
            bf16x8 afrag;
            #pragma unroll
            for (int t = 0; t < 4; ++t) {
                afrag[t]     = f2bf_rne(lo[j][t]);
                afrag[t + 4] = f2bf_rne(hi[j][t]);
            }
            const unsigned short* wk = wT + (g * 9 + j) * (COUT * CIN) + row16 * CIN + quad * 8;
            #pragma unroll
            for (int ct = 0; ct < 4; ++ct) {
                bf16x8 bfrag = *(const bf16x8*)(wk + ct * 16 * CIN);
                acc[ct] = __builtin_amdgcn_mfma_f32_16x16x32_bf16(afrag, bfrag, acc[ct], 0, 0, 0);
            }
        }
    }

    // ---- epilogue with discovered (m,n) mapping ----
    const int tilebase = blockIdx.x * 64 + wave * 16;
    #pragma unroll
    for (int ct = 0; ct < 4; ++ct) {
        #pragma unroll
        for (int r = 0; r < 4; ++r) {
            int n_out = tilebase + mrow[r];
            if (n_out < N_NODES)
                out[(size_t)n_out * COUT + ct * 16 + ncol[r]] = acc[ct][r];
        }
    }
}

// ---------------------------------------------------------------------------
// BN stats over out[N][64]: coalesced float4 sweep, LDS reduce, split atomics
// ---------------------------------------------------------------------------
__global__ __launch_bounds__(256) void stats_pass(const float* __restrict__ out,
                                                  float* __restrict__ stats) {
    __shared__ float lsum[COUT];
    __shared__ float lsq[COUT];
    if (threadIdx.x < COUT) { lsum[threadIdx.x] = 0.f; lsq[threadIdx.x] = 0.f; }
    __syncthreads();

    const int j = threadIdx.x & 15;
    int row = blockIdx.x * 16 + (threadIdx.x >> 4);
    const int rstride = gridDim.x * 16;
    float s0=0,s1=0,s2=0,s3=0,q0=0,q1=0,q2=0,q3=0;
    for (; row < N_NODES; row += rstride) {
        f32x4 v = ((const f32x4*)out)[row * 16 + j];
        s0 += v[0]; q0 += v[0]*v[0];
        s1 += v[1]; q1 += v[1]*v[1];
        s2 += v[2]; q2 += v[2]*v[2];
        s3 += v[3]; q3 += v[3]*v[3];
    }
    atomicAdd(&lsum[j*4+0], s0); atomicAdd(&lsq[j*4+0], q0);
    atomicAdd(&lsum[j*4+1], s1); atomicAdd(&lsq[j*4+1], q1);
    atomicAdd(&lsum[j*4+2], s2); atomicAdd(&lsq[j*4+2], q2);
    atomicAdd(&lsum[j*4+3], s3); atomicAdd(&lsq[j*4+3], q3);
    __syncthreads();

    if (threadIdx.x < 128) {
        int split = blockIdx.x & (N_SPLITS - 1);
        float v = (threadIdx.x < 64) ? lsum[threadIdx.x] : lsq[threadIdx.x - 64];
        atomicAdd(&stats[split * 128 + threadIdx.x], v);
    }
}

// ---------------------------------------------------------------------------
__global__ void finalize_stats(const float* __restrict__ stats,
                               const float* __restrict__ gamma,
                               const float* __restrict__ beta,
                               float* __restrict__ ab) {
    int o = threadIdx.x;  // 64 threads
    if (o >= COUT) return;
    float s = 0.f, q = 0.f;
    for (int sp = 0; sp < N_SPLITS; ++sp) {
        s += stats[sp * 128 + o];
        q += stats[sp * 128 + 64 + o];
    }
    float inv_n = 1.0f / (float)N_NODES;
    float mean = s * inv_n;
    float var  = q * inv_n - mean * mean;
    float a = gamma[o] * rsqrtf(var + BN_EPS);
    float b = beta[o] - mean * a;
    ab[o] = a;
    ab[64 + o] = b;
}

// ---------------------------------------------------------------------------
__global__ __launch_bounds__(256) void bn_relu(float* __restrict__ out,
                                               const float* __restrict__ ab) {
    int i = blockIdx.x * blockDim.x + threadIdx.x;  // float4 index, exact grid
    f32x4 a = ((const f32x4*)ab)[i & 15];
    f32x4 b = ((const f32x4*)(ab + 64))[i & 15];
    f32x4 v = ((f32x4*)out)[i];
    #pragma unroll
    for (int j = 0; j < 4; ++j) {
        float y = v[j] * a[j] + b[j];
        v[j] = y > 0.f ? y : 0.f;
    }
    ((f32x4*)out)[i] = v;
}

// ---------------------------------------------------------------------------
extern "C" void kernel_launch(void* const* d_in, const int* in_sizes, int n_in,
                              void* d_out, int out_size, void* d_ws, size_t ws_size,
                              hipStream_t stream) {
    const float* data   = (const float*)d_in[0];
    const int*   neigh  = (const int*)d_in[1];     // int32 on device
    const float* weight = (const float*)d_in[2];
    const float* gamma  = (const float*)d_in[3];
    const float* beta   = (const float*)d_in[4];
    float* out = (float*)d_out;

    char* ws = (char*)d_ws;
    float*          stats = (float*)(ws + WS_STATS_OFF);
    float*          ab    = (float*)(ws + WS_AB_OFF);
    unsigned short* wT    = (unsigned short*)(ws + WS_WT_OFF);

    prep<<<(K_STENCIL * COUT * CIN + 255) / 256, 256, 0, stream>>>(weight, wT, stats);

    const int grid = (N_NODES + 63) / 64;  // 4688
    conv_mfma<<<grid, 256, 0, stream>>>(data, neigh, wT, out);

    stats_pass<<<1024, 256, 0, stream>>>(out, stats);
    finalize_stats<<<1, 64, 0, stream>>>(stats, gamma, beta, ab);

    int total4 = N_NODES * COUT / 4;  // 4,800,000
    bn_relu<<<total4 / 256, 256, 0, stream>>>(out, ab);
}